// Round 6
// baseline (2367.572 us; speedup 1.0000x reference)
//
#include <hip/hip_runtime.h>
#include <hip/hip_bf16.h>

// ---------------------------------------------------------------------------
// Nystrom attention: split-bf16 (hi/lo, 3xMFMA) GEMMs everywhere.
// R6: single sw-barrier mega-kernel for scores+softmax+zinit+24 pinv GEMMs+t2
//     (37 -> 8 launches); cvt-based split; LDS stride 40->36.
// B=4, N=4096, DIM=512, H=8, DH=64, M=256, l=16, 6 pinv iters, conv K=33.
// ---------------------------------------------------------------------------

typedef __attribute__((ext_vector_type(8))) short bf16x8;
typedef __attribute__((ext_vector_type(4))) float f32x4;

constexpr size_t SQ = 8388608;   // 32*4096*64
constexpr size_t SL = 524288;    // 32*256*64
constexpr size_t SA = 2097152;   // 32*256*256
constexpr size_t SP = 1048576;   // one bf16 plane of SA (float units)

constexpr size_t O_Q    = 0;                   // q -> later oh (in-place)
constexpr size_t O_K    = O_Q + SQ;            // k -> later zA,zB (f32)
constexpr size_t O_V    = O_K + SQ;
constexpr size_t O_QL   = O_V + SQ;
constexpr size_t O_KL   = O_QL + SL;
constexpr size_t O_A2   = O_KL + SL;
constexpr size_t O_T1   = O_A2 + SA;
constexpr size_t O_RS3  = O_T1 + SL;
constexpr size_t O_SCAL = O_RS3 + 8192;        // scal[0..15]; bar = scal+8
constexpr size_t O_T2   = O_SCAL + 16;         // first 8192 floats double as colsum
constexpr size_t O_ZT0  = O_T2 + SL;
constexpr size_t O_ZT1  = O_ZT0 + 2 * SP;      // vT planes alias ZT1..Y2T (pre-pinv)
constexpr size_t O_XZT  = O_ZT1 + 2 * SP;      // t2T planes alias ZT1 (post-pinv)
constexpr size_t O_Y1T  = O_XZT + 2 * SP;
constexpr size_t O_Y2T  = O_Y1T + 2 * SP;
constexpr size_t O_WQT  = O_Y2T + 2 * SP;
constexpr size_t O_WOT  = O_WQT + 786432;
constexpr size_t O_END  = O_WOT + 262144;      // ~41M floats ~164 MB

// ---------------------------------------------------------------------------
__device__ __forceinline__ unsigned short bf16_rn(float x) {
    __hip_bfloat16 b = __float2bfloat16(x);    // HW RNE cvt
    unsigned short u;
    __builtin_memcpy(&u, &b, 2);
    return u;
}

__device__ __forceinline__ void split2(float x, unsigned short& h,
                                       unsigned short& l) {
    h = bf16_rn(x);
    float hf = __uint_as_float((unsigned)h << 16);
    l = bf16_rn(x - hf);
}

__device__ __forceinline__ void split_pack4(float a, float b, float c, float d,
                                            uint2& ph, uint2& pl) {
    unsigned short h0 = bf16_rn(a), h1 = bf16_rn(b);
    unsigned short h2 = bf16_rn(c), h3 = bf16_rn(d);
    ph.x = (unsigned)h0 | ((unsigned)h1 << 16);
    ph.y = (unsigned)h2 | ((unsigned)h3 << 16);
    float fa = __uint_as_float((unsigned)h0 << 16);
    float fb = __uint_as_float((unsigned)h1 << 16);
    float fc = __uint_as_float((unsigned)h2 << 16);
    float fd = __uint_as_float((unsigned)h3 << 16);
    unsigned short l0 = bf16_rn(a - fa), l1 = bf16_rn(b - fb);
    unsigned short l2 = bf16_rn(c - fc), l3 = bf16_rn(d - fd);
    pl.x = (unsigned)l0 | ((unsigned)l1 << 16);
    pl.y = (unsigned)l2 | ((unsigned)l3 << 16);
}

__device__ __forceinline__ void stage_split4(float4 av, unsigned short* H,
                                             unsigned short* L, int off) {
    uint2 ph, pl;
    split_pack4(av.x, av.y, av.z, av.w, ph, pl);
    *(uint2*)&H[off] = ph;
    *(uint2*)&L[off] = pl;
}

__device__ __forceinline__ f32x4 mfma3(bf16x8 ah, bf16x8 al, bf16x8 bh,
                                       bf16x8 bl, f32x4 c) {
    c = __builtin_amdgcn_mfma_f32_16x16x32_bf16(ah, bh, c, 0, 0, 0);
    c = __builtin_amdgcn_mfma_f32_16x16x32_bf16(ah, bl, c, 0, 0, 0);
    c = __builtin_amdgcn_mfma_f32_16x16x32_bf16(al, bh, c, 0, 0, 0);
    return c;
}

// fp32 64x64 micro-kernel (BK=16, stride 68)
__device__ __forceinline__ void mt16(const float* As, const float* Bs,
                                     int ty4, int tx4, float (&acc)[4][4]) {
#pragma unroll
    for (int kk = 0; kk < 16; ++kk) {
        float4 a4 = *(const float4*)(As + kk * 68 + ty4);
        float4 b4 = *(const float4*)(Bs + kk * 68 + tx4);
        float aa[4] = {a4.x, a4.y, a4.z, a4.w};
        float bb[4] = {b4.x, b4.y, b4.z, b4.w};
#pragma unroll
        for (int u = 0; u < 4; ++u)
#pragma unroll
            for (int w = 0; w < 4; ++w)
                acc[u][w] += aa[u] * bb[w];
    }
}

// software grid barrier (grid must be fully resident; 256 blocks on 256 CUs)
__device__ __forceinline__ void gsync(unsigned* bar, unsigned& phase) {
    __syncthreads();
    if (threadIdx.x == 0) {
        __threadfence();
        phase += 256;
        atomicAdd(bar, 1u);
        while (__hip_atomic_load(bar, __ATOMIC_RELAXED,
                                 __HIP_MEMORY_SCOPE_AGENT) < phase)
            __builtin_amdgcn_s_sleep(2);
    }
    __syncthreads();
    __threadfence();
}

// ---------------------------------------------------------------------------
// qkv MFMA GEMM: x[16384,512] @ w_qkv planes; scatters q(*0.125)/k/v AND
// emits vT split-bf16 planes [bh][dh][4096].  grid (12, 128).
// ---------------------------------------------------------------------------
__global__ __launch_bounds__(256) void mfma_qkv(
    const float* __restrict__ X, const unsigned short* __restrict__ WTh,
    const unsigned short* __restrict__ WTl, float* __restrict__ qb,
    float* __restrict__ kb, float* __restrict__ vb,
    unsigned short* __restrict__ vTh, unsigned short* __restrict__ vTl) {
    __shared__ unsigned short Ah[128 * 36], Al[128 * 36];
    __shared__ unsigned short Bh[128 * 36], Bl[128 * 36];
    const int t = threadIdx.x;
    const int wave = t >> 6, lane = t & 63, lm = lane & 15, lq = lane >> 4;
    const int m0 = blockIdx.y * 128, n0 = blockIdx.x * 128;
    const int mb = (wave >> 1) * 64, nb = (wave & 1) * 64;
    f32x4 acc[4][4];
#pragma unroll
    for (int i = 0; i < 4; ++i)
#pragma unroll
        for (int j = 0; j < 4; ++j) acc[i][j] = (f32x4){0.f, 0.f, 0.f, 0.f};

    for (int kt = 0; kt < 512; kt += 32) {
#pragma unroll
        for (int r = 0; r < 4; ++r) {
            int id = t + r * 256, row = id >> 3, k4 = (id & 7) * 4;
            float4 av = *(const float4*)(X + (size_t)(m0 + row) * 512 + kt + k4);
            stage_split4(av, Ah, Al, row * 36 + k4);
        }
#pragma unroll
        for (int r = 0; r < 2; ++r) {
            int id = t + r * 256, row = id >> 2, ko = (id & 3) * 8;
            *(uint4*)&Bh[row * 36 + ko] =
                *(const uint4*)(WTh + (size_t)(n0 + row) * 512 + kt + ko);
            *(uint4*)&Bl[row * 36 + ko] =
                *(const uint4*)(WTl + (size_t)(n0 + row) * 512 + kt + ko);
        }
        __syncthreads();
        bf16x8 ah[4], al[4], bh[4], bl[4];
#pragma unroll
        for (int i = 0; i < 4; ++i) {
            ah[i] = *(const bf16x8*)&Ah[(mb + i * 16 + lm) * 36 + lq * 8];
            al[i] = *(const bf16x8*)&Al[(mb + i * 16 + lm) * 36 + lq * 8];
        }
#pragma unroll
        for (int j = 0; j < 4; ++j) {
            bh[j] = *(const bf16x8*)&Bh[(nb + j * 16 + lm) * 36 + lq * 8];
            bl[j] = *(const bf16x8*)&Bl[(nb + j * 16 + lm) * 36 + lq * 8];
        }
#pragma unroll
        for (int i = 0; i < 4; ++i)
#pragma unroll
            for (int j = 0; j < 4; ++j)
                acc[i][j] = mfma3(ah[i], al[i], bh[j], bl[j], acc[i][j]);
        __syncthreads();
    }
#pragma unroll
    for (int i = 0; i < 4; ++i)
#pragma unroll
        for (int j = 0; j < 4; ++j) {
            int r0 = m0 + mb + i * 16 + lq * 4;
            int c  = n0 + nb + j * 16 + lm;
            int which = c >> 9, h = (c >> 6) & 7, d = c & 63;
            float sc = (which == 0) ? 0.125f : 1.0f;
            float* dst = (which == 0) ? qb : (which == 1 ? kb : vb);
            int b = r0 >> 12, nbase = r0 & 4095;
#pragma unroll
            for (int e = 0; e < 4; ++e)
                dst[(size_t)(b * 8 + h) * 262144 + (size_t)(nbase + e) * 64 + d] =
                    acc[i][j][e] * sc;
            if (which == 2) {
                uint2 ph, pl;
                split_pack4(acc[i][j][0], acc[i][j][1], acc[i][j][2],
                            acc[i][j][3], ph, pl);
                size_t off = ((size_t)(b * 8 + h) * 64 + d) * 4096 + nbase;
                *(uint2*)&vTh[off] = ph;
                *(uint2*)&vTl[off] = pl;
            }
        }
}

// ---------------------------------------------------------------------------
// final MFMA GEMM: out[16384,512] = oh(gathered) @ w_out planes. grid (4,128)
// ---------------------------------------------------------------------------
__global__ __launch_bounds__(256) void mfma_final(
    const float* __restrict__ OH, const unsigned short* __restrict__ WTh,
    const unsigned short* __restrict__ WTl, float* __restrict__ out) {
    __shared__ unsigned short Ah[128 * 36], Al[128 * 36];
    __shared__ unsigned short Bh[128 * 36], Bl[128 * 36];
    const int t = threadIdx.x;
    const int wave = t >> 6, lane = t & 63, lm = lane & 15, lq = lane >> 4;
    const int m0 = blockIdx.y * 128, n0 = blockIdx.x * 128;
    const int mb = (wave >> 1) * 64, nb = (wave & 1) * 64;
    f32x4 acc[4][4];
#pragma unroll
    for (int i = 0; i < 4; ++i)
#pragma unroll
        for (int j = 0; j < 4; ++j) acc[i][j] = (f32x4){0.f, 0.f, 0.f, 0.f};

    for (int kt = 0; kt < 512; kt += 32) {
#pragma unroll
        for (int r = 0; r < 4; ++r) {
            int id = t + r * 256, row = id >> 3, k4g = kt + (id & 7) * 4;
            int gr = m0 + row, b = gr >> 12, n = gr & 4095;
            float4 av = *(const float4*)(OH + (size_t)(b * 8 + (k4g >> 6)) * 262144 +
                                         (size_t)n * 64 + (k4g & 63));
            stage_split4(av, Ah, Al, row * 36 + (id & 7) * 4);
        }
#pragma unroll
        for (int r = 0; r < 2; ++r) {
            int id = t + r * 256, row = id >> 2, ko = (id & 3) * 8;
            *(uint4*)&Bh[row * 36 + ko] =
                *(const uint4*)(WTh + (size_t)(n0 + row) * 512 + kt + ko);
            *(uint4*)&Bl[row * 36 + ko] =
                *(const uint4*)(WTl + (size_t)(n0 + row) * 512 + kt + ko);
        }
        __syncthreads();
        bf16x8 ah[4], al[4], bh[4], bl[4];
#pragma unroll
        for (int i = 0; i < 4; ++i) {
            ah[i] = *(const bf16x8*)&Ah[(mb + i * 16 + lm) * 36 + lq * 8];
            al[i] = *(const bf16x8*)&Al[(mb + i * 16 + lm) * 36 + lq * 8];
        }
#pragma unroll
        for (int j = 0; j < 4; ++j) {
            bh[j] = *(const bf16x8*)&Bh[(nb + j * 16 + lm) * 36 + lq * 8];
            bl[j] = *(const bf16x8*)&Bl[(nb + j * 16 + lm) * 36 + lq * 8];
        }
#pragma unroll
        for (int i = 0; i < 4; ++i)
#pragma unroll
            for (int j = 0; j < 4; ++j)
                acc[i][j] = mfma3(ah[i], al[i], bh[j], bl[j], acc[i][j]);
        __syncthreads();
    }
#pragma unroll
    for (int i = 0; i < 4; ++i)
#pragma unroll
        for (int j = 0; j < 4; ++j) {
            int r0 = m0 + mb + i * 16 + lq * 4;
            int c  = n0 + nb + j * 16 + lm;
#pragma unroll
            for (int e = 0; e < 4; ++e)
                out[(size_t)(r0 + e) * 512 + c] = acc[i][j][e];
        }
}

// ---------------------------------------------------------------------------
// F3 MFMA: t1 += exp(qland@k^T)@v, rs3 += rowsums. grid (8, 4, 32).
// ---------------------------------------------------------------------------
__global__ __launch_bounds__(256) void attn3v_mfma(
    const float* __restrict__ qland, const float* __restrict__ k,
    const unsigned short* __restrict__ vTh,
    const unsigned short* __restrict__ vTl,
    float* __restrict__ t1, float* __restrict__ rs3) {
    __shared__ unsigned short Qh[4608], Ql[4608];
    __shared__ unsigned short Kh[4608], Kl[4608];
    __shared__ unsigned short Eh[4608], El[4608];
    const int t = threadIdx.x;
    const int wave = t >> 6, lane = t & 63, lm = lane & 15, lq = lane >> 4;
    const int bz = blockIdx.z, m0 = blockIdx.y * 64, c0 = blockIdx.x * 8;
    const float* qb = qland + (size_t)bz * 16384;
    const float* kb = k + (size_t)bz * 262144;
    const unsigned short* vhb = vTh + (size_t)bz * 262144;
    const unsigned short* vlb = vTl + (size_t)bz * 262144;
#pragma unroll
    for (int r = 0; r < 4; ++r) {
        int id = t + r * 256, row = id >> 4, d4 = (id & 15) * 4;
        float4 av = *(const float4*)(qb + (size_t)(m0 + row) * 64 + d4);
        stage_split4(av, Qh, Ql, row * 72 + d4);
    }
    f32x4 acc[4];
#pragma unroll
    for (int j = 0; j < 4; ++j) acc[j] = (f32x4){0.f, 0.f, 0.f, 0.f};
    float rsum[4] = {0.f, 0.f, 0.f, 0.f};
    __syncthreads();

    for (int c = c0; c < c0 + 8; ++c) {
        const int tok0 = c * 64;
#pragma unroll
        for (int r = 0; r < 4; ++r) {
            int id = t + r * 256, row = id >> 4, d4 = (id & 15) * 4;
            float4 kv = *(const float4*)(kb + (size_t)(tok0 + row) * 64 + d4);
            stage_split4(kv, Kh, Kl, row * 72 + d4);
        }
        __syncthreads();
        bf16x8 a0  = *(const bf16x8*)&Qh[(wave * 16 + lm) * 72 + lq * 8];
        bf16x8 a0l = *(const bf16x8*)&Ql[(wave * 16 + lm) * 72 + lq * 8];
        bf16x8 a1  = *(const bf16x8*)&Qh[(wave * 16 + lm) * 72 + 32 + lq * 8];
        bf16x8 a1l = *(const bf16x8*)&Ql[(wave * 16 + lm) * 72 + 32 + lq * 8];
        f32x4 s[4];
#pragma unroll
        for (int j = 0; j < 4; ++j) s[j] = (f32x4){0.f, 0.f, 0.f, 0.f};
#pragma unroll
        for (int j = 0; j < 4; ++j) {
            bf16x8 b0  = *(const bf16x8*)&Kh[(j * 16 + lm) * 72 + lq * 8];
            bf16x8 b0l = *(const bf16x8*)&Kl[(j * 16 + lm) * 72 + lq * 8];
            bf16x8 b1  = *(const bf16x8*)&Kh[(j * 16 + lm) * 72 + 32 + lq * 8];
            bf16x8 b1l = *(const bf16x8*)&Kl[(j * 16 + lm) * 72 + 32 + lq * 8];
            s[j] = mfma3(a0, a0l, b0, b0l, s[j]);
            s[j] = mfma3(a1, a1l, b1, b1l, s[j]);
        }
        __syncthreads();
#pragma unroll
        for (int j = 0; j < 4; ++j)
#pragma unroll
            for (int e = 0; e < 4; ++e) {
                float ev = __expf(s[j][e]);
                rsum[e] += ev;
                unsigned short h, l;
                split2(ev, h, l);
                int off = (wave * 16 + lq * 4 + e) * 72 + j * 16 + lm;
                Eh[off] = h;
                El[off] = l;
            }
#pragma unroll
        for (int r = 0; r < 2; ++r) {
            int id = t + r * 256, dh = id >> 3, t8 = (id & 7) * 8;
            *(uint4*)&Kh[dh * 72 + t8] =
                *(const uint4*)(vhb + (size_t)dh * 4096 + tok0 + t8);
            *(uint4*)&Kl[dh * 72 + t8] =
                *(const uint4*)(vlb + (size_t)dh * 4096 + tok0 + t8);
        }
        __syncthreads();
        bf16x8 e0  = *(const bf16x8*)&Eh[(wave * 16 + lm) * 72 + lq * 8];
        bf16x8 e0l = *(const bf16x8*)&El[(wave * 16 + lm) * 72 + lq * 8];
        bf16x8 e1  = *(const bf16x8*)&Eh[(wave * 16 + lm) * 72 + 32 + lq * 8];
        bf16x8 e1l = *(const bf16x8*)&El[(wave * 16 + lm) * 72 + 32 + lq * 8];
#pragma unroll
        for (int j = 0; j < 4; ++j) {
            bf16x8 v0  = *(const bf16x8*)&Kh[(j * 16 + lm) * 72 + lq * 8];
            bf16x8 v0l = *(const bf16x8*)&Kl[(j * 16 + lm) * 72 + lq * 8];
            bf16x8 v1  = *(const bf16x8*)&Kh[(j * 16 + lm) * 72 + 32 + lq * 8];
            bf16x8 v1l = *(const bf16x8*)&Kl[(j * 16 + lm) * 72 + 32 + lq * 8];
            acc[j] = mfma3(e0, e0l, v0, v0l, acc[j]);
            acc[j] = mfma3(e1, e1l, v1, v1l, acc[j]);
        }
        __syncthreads();
    }
    float* t1b = t1 + (size_t)bz * 16384;
#pragma unroll
    for (int j = 0; j < 4; ++j)
#pragma unroll
        for (int e = 0; e < 4; ++e)
            atomicAdd(t1b + (size_t)(m0 + wave * 16 + lq * 4 + e) * 64 +
                          j * 16 + lm,
                      acc[j][e]);
#pragma unroll
    for (int e = 0; e < 4; ++e) {
        float vs = rsum[e];
        for (int mm = 1; mm < 16; mm <<= 1) vs += __shfl_xor(vs, mm);
        if (lm == 0)
            atomicAdd(rs3 + bz * 256 + m0 + wave * 16 + lq * 4 + e, vs);
    }
}

// ---------------------------------------------------------------------------
// F1 MFMA: oh = softmax(q@kland^T) @ t2 (normalized), in-place over q.
// grid (64, 32).
// ---------------------------------------------------------------------------
__global__ __launch_bounds__(256) void attn1t2_mfma(
    const float* __restrict__ q, const float* __restrict__ kland,
    const unsigned short* __restrict__ t2Th,
    const unsigned short* __restrict__ t2Tl, float* __restrict__ oh) {
    __shared__ unsigned short Qh[4608], Ql[4608];
    __shared__ unsigned short Kh[4608], Kl[4608];
    __shared__ unsigned short Eh[4608], El[4608];
    const int t = threadIdx.x;
    const int wave = t >> 6, lane = t & 63, lm = lane & 15, lq = lane >> 4;
    const int bz = blockIdx.y, m0 = blockIdx.x * 64;
    const float* qb  = q + (size_t)bz * 262144;
    const float* klb = kland + (size_t)bz * 16384;
    const unsigned short* t2h = t2Th + (size_t)bz * 16384;
    const unsigned short* t2l = t2Tl + (size_t)bz * 16384;
#pragma unroll
    for (int r = 0; r < 4; ++r) {
        int id = t + r * 256, row = id >> 4, d4 = (id & 15) * 4;
        float4 av = *(const float4*)(qb + (size_t)(m0 + row) * 64 + d4);
        stage_split4(av, Qh, Ql, row * 72 + d4);
    }
    f32x4 acc[4];
#pragma unroll
    for (int j = 0; j < 4; ++j) acc[j] = (f32x4){0.f, 0.f, 0.f, 0.f};
    float rsum[4] = {0.f, 0.f, 0.f, 0.f};
    __syncthreads();

    for (int lc = 0; lc < 4; ++lc) {
        const int l0 = lc * 64;
#pragma unroll
        for (int r = 0; r < 4; ++r) {
            int id = t + r * 256, row = id >> 4, d4 = (id & 15) * 4;
            float4 kv = *(const float4*)(klb + (size_t)(l0 + row) * 64 + d4);
            stage_split4(kv, Kh, Kl, row * 72 + d4);
        }
        __syncthreads();
        bf16x8 a0  = *(const bf16x8*)&Qh[(wave * 16 + lm) * 72 + lq * 8];
        bf16x8 a0l = *(const bf16x8*)&Ql[(wave * 16 + lm) * 72 + lq * 8];
        bf16x8 a1  = *(const bf16x8*)&Qh[(wave * 16 + lm) * 72 + 32 + lq * 8];
        bf16x8 a1l = *(const bf16x8*)&Ql[(wave * 16 + lm) * 72 + 32 + lq * 8];
        f32x4 s[4];
#pragma unroll
        for (int j = 0; j < 4; ++j) s[j] = (f32x4){0.f, 0.f, 0.f, 0.f};
#pragma unroll
        for (int j = 0; j < 4; ++j) {
            bf16x8 b0  = *(const bf16x8*)&Kh[(j * 16 + lm) * 72 + lq * 8];
            bf16x8 b0l = *(const bf16x8*)&Kl[(j * 16 + lm) * 72 + lq * 8];
            bf16x8 b1  = *(const bf16x8*)&Kh[(j * 16 + lm) * 72 + 32 + lq * 8];
            bf16x8 b1l = *(const bf16x8*)&Kl[(j * 16 + lm) * 72 + 32 + lq * 8];
            s[j] = mfma3(a0, a0l, b0, b0l, s[j]);
            s[j] = mfma3(a1, a1l, b1, b1l, s[j]);
        }
        __syncthreads();
#pragma unroll
        for (int j = 0; j < 4; ++j)
#pragma unroll
            for (int e = 0; e < 4; ++e) {
                float ev = __expf(s[j][e]);
                rsum[e] += ev;
                unsigned short h, l;
                split2(ev, h, l);
                int off = (wave * 16 + lq * 4 + e) * 72 + j * 16 + lm;
                Eh[off] = h;
                El[off] = l;
            }
#pragma unroll
        for (int r = 0; r < 2; ++r) {
            int id = t + r * 256, dh = id >> 3, t8 = (id & 7) * 8;
            *(uint4*)&Kh[dh * 72 + t8] =
                *(const uint4*)(t2h + (size_t)dh * 256 + l0 + t8);
            *(uint4*)&Kl[dh * 72 + t8] =
                *(const uint4*)(t2l + (size_t)dh * 256 + l0 + t8);
        }
        __syncthreads();
        bf16x8 e0  = *(const bf16x8*)&Eh[(wave * 16 + lm) * 72 + lq * 8];
        bf16x8 e0l = *(const bf16x8*)&El[(wave * 16 + lm) * 72 + lq * 8];
        bf16x8 e1  = *(const bf16x8*)&Eh[(wave * 16 + lm) * 72 + 32 + lq * 8];
        bf16x8 e1l = *(const bf16x8*)&El[(wave * 16 + lm) * 72 + 32 + lq * 8];
#pragma unroll
        for (int j = 0; j < 4; ++j) {
            bf16x8 v0  = *(const bf16x8*)&Kh[(j * 16 + lm) * 72 + lq * 8];
            bf16x8 v0l = *(const bf16x8*)&Kl[(j * 16 + lm) * 72 + lq * 8];
            bf16x8 v1  = *(const bf16x8*)&Kh[(j * 16 + lm) * 72 + 32 + lq * 8];
            bf16x8 v1l = *(const bf16x8*)&Kl[(j * 16 + lm) * 72 + 32 + lq * 8];
            acc[j] = mfma3(e0, e0l, v0, v0l, acc[j]);
            acc[j] = mfma3(e1, e1l, v1, v1l, acc[j]);
        }
        __syncthreads();
    }
    float rinv[4];
#pragma unroll
    for (int e = 0; e < 4; ++e) {
        float vs = rsum[e];
        for (int mm = 1; mm < 16; mm <<= 1) vs += __shfl_xor(vs, mm);
        rinv[e] = 1.0f / vs;
    }
    float* ohb = oh + (size_t)bz * 262144;
#pragma unroll
    for (int j = 0; j < 4; ++j)
#pragma unroll
        for (int e = 0; e < 4; ++e)
            ohb[(size_t)(m0 + wave * 16 + lq * 4 + e) * 64 + j * 16 + lm] =
                acc[j][e] * rinv[e];
}

// ---------------------------------------------------------------------------
// pinv GEMM stage (device fn): 64x128 tile of C = alpha*(A@B) + beta*A_elem.
// A fp32 [32][256][256]; B planes BT[n][k]; writes C f32 (opt) + CT planes.
// ---------------------------------------------------------------------------
__device__ __forceinline__ void pinv_stage(
    const float* __restrict__ A, const unsigned short* __restrict__ BTh,
    const unsigned short* __restrict__ BTl, float* __restrict__ C,
    unsigned short* __restrict__ CTh, unsigned short* __restrict__ CTl,
    int bh, int m0, int n0, int epi, float alpha, float beta,
    unsigned short* Ah, unsigned short* Al, unsigned short* Bh,
    unsigned short* Bl, int t) {
    const int wave = t >> 6, lane = t & 63, lm = lane & 15, lq = lane >> 4;
    const float* Ab = A + (size_t)bh * 65536;
    const unsigned short* BhB = BTh + (size_t)bh * 65536;
    const unsigned short* BlB = BTl + (size_t)bh * 65536;
    f32x4 acc[8];
#pragma unroll
    for (int j = 0; j < 8; ++j) acc[j] = (f32x4){0.f, 0.f, 0.f, 0.f};

    for (int kt = 0; kt < 256; kt += 32) {
#pragma unroll
        for (int r = 0; r < 2; ++r) {
            int id = t + r * 256, row = id >> 3, k4 = (id & 7) * 4;
            float4 av = *(const float4*)(Ab + (size_t)(m0 + row) * 256 + kt + k4);
            stage_split4(av, Ah, Al, row * 36 + k4);
        }
#pragma unroll
        for (int r = 0; r < 2; ++r) {
            int id = t + r * 256, row = id >> 2, ko = (id & 3) * 8;
            *(uint4*)&Bh[row * 36 + ko] =
                *(const uint4*)(BhB + (size_t)(n0 + row) * 256 + kt + ko);
            *(uint4*)&Bl[row * 36 + ko] =
                *(const uint4*)(BlB + (size_t)(n0 + row) * 256 + kt + ko);
        }
        __syncthreads();
        bf16x8 ah = *(const bf16x8*)&Ah[(wave * 16 + lm) * 36 + lq * 8];
        bf16x8 al = *(const bf16x8*)&Al[(wave * 16 + lm) * 36 + lq * 8];
#pragma unroll
        for (int j = 0; j < 8; ++j) {
            bf16x8 bhv = *(const bf16x8*)&Bh[(j * 16 + lm) * 36 + lq * 8];
            bf16x8 blv = *(const bf16x8*)&Bl[(j * 16 + lm) * 36 + lq * 8];
            acc[j] = mfma3(ah, al, bhv, blv, acc[j]);
        }
        __syncthreads();
    }

    const int r0 = m0 + wave * 16 + lq * 4;
#pragma unroll
    for (int j = 0; j < 8; ++j) {
        int c = n0 + j * 16 + lm;
        float vals[4] = {acc[j][0], acc[j][1], acc[j][2], acc[j][3]};
        if (epi) {
#pragma unroll
            for (int e = 0; e < 4; ++e)
                vals[e] = alpha * vals[e] + beta * Ab[(size_t)(r0 + e) * 256 + c];
        }
        if (C) {
#pragma unroll
            for (int e = 0; e < 4; ++e)
                C[(size_t)bh * 65536 + (size_t)(r0 + e) * 256 + c] = vals[e];
        }
        uint2 ph, pl;
        split_pack4(vals[0], vals[1], vals[2], vals[3], ph, pl);
        size_t off = (size_t)bh * 65536 + (size_t)c * 256 + r0;
        *(uint2*)&CTh[off] = ph;
        *(uint2*)&CTl[off] = pl;
    }
}

// ---------------------------------------------------------------------------
// mega-kernel: scores -> softmax(+colsum) -> denom -> zinit -> 24 NS stages
// -> t2.  grid 256 blocks (1/CU, fully resident), sw grid barrier.
// ---------------------------------------------------------------------------
__global__ __launch_bounds__(256) void coop_pinv(
    float* __restrict__ attn2, const float* __restrict__ qland,
    const float* __restrict__ kland, float* __restrict__ zA,
    float* __restrict__ zB,
    unsigned short* ZT0h, unsigned short* ZT0l,
    unsigned short* ZT1h, unsigned short* ZT1l,
    unsigned short* XZTh, unsigned short* XZTl,
    unsigned short* Y1Th, unsigned short* Y1Tl,
    unsigned short* Y2Th, unsigned short* Y2Tl,
    const float* __restrict__ t1, const float* __restrict__ rs3,
    float* __restrict__ t2, unsigned short* t2Th, unsigned short* t2Tl,
    float* __restrict__ colsum, float* __restrict__ scal,
    unsigned* __restrict__ bar) {
    __shared__ __align__(16) unsigned char smem[27648];
    unsigned short* Ah = (unsigned short*)smem;
    unsigned short* Al = Ah + 64 * 36;
    unsigned short* Bh = Al + 64 * 36;
    unsigned short* Bl = Bh + 128 * 36;
    float* As = (float*)smem;
    float* Bs = As + 16 * 68;
    float* Lf = (float*)smem;

    const int t = threadIdx.x;
    const int gid = blockIdx.x;
    const int bh = gid >> 3;
    const int mt = (gid >> 1) & 3;
    const int nt = gid & 1;
    const int m0 = mt * 64, n0 = nt * 128;
    unsigned phase = 0;

    // ---- Phase 0: attn2 = qland @ kland^T (two 64x64 sub-tiles) ----
    {
        const float* Aq = qland + (size_t)bh * 16384;
        const float* Bk = kland + (size_t)bh * 16384;
        float* Cb = attn2 + (size_t)bh * 65536;
        const int tx4 = (t & 15) * 4, ty4 = (t >> 4) * 4;
        const int ar = t >> 2, ak = (t & 3) * 4;
        for (int ns = 0; ns < 2; ++ns) {
            int n0s = n0 + ns * 64;
            float acc[4][4] = {};
            for (int kt = 0; kt < 64; kt += 16) {
                float4 av = *(const float4*)(Aq + (size_t)(m0 + ar) * 64 + kt + ak);
                float4 bv = *(const float4*)(Bk + (size_t)(n0s + ar) * 64 + kt + ak);
                As[(ak + 0) * 68 + ar] = av.x;
                As[(ak + 1) * 68 + ar] = av.y;
                As[(ak + 2) * 68 + ar] = av.z;
                As[(ak + 3) * 68 + ar] = av.w;
                Bs[(ak + 0) * 68 + ar] = bv.x;
                Bs[(ak + 1) * 68 + ar] = bv.y;
                Bs[(ak + 2) * 68 + ar] = bv.z;
                Bs[(ak + 3) * 68 + ar] = bv.w;
                __syncthreads();
                mt16(As, Bs, ty4, tx4, acc);
                __syncthreads();
            }
#pragma unroll
            for (int u = 0; u < 4; ++u)
                *(float4*)(Cb + (size_t)(m0 + ty4 + u) * 256 + n0s + tx4) =
                    make_float4(acc[u][0], acc[u][1], acc[u][2], acc[u][3]);
        }
    }
    gsync(bar, phase);

    // ---- Phase 1: row softmax + column-sum accumulation ----
    if (nt == 0) {
        float* ab = attn2 + (size_t)bh * 65536;
        const int wave = t >> 6, lane = t & 63;
        float csum[4] = {0.f, 0.f, 0.f, 0.f};
        for (int rr = 0; rr < 16; ++rr) {
            int row = m0 + wave * 16 + rr;
            float4 v4 = *(float4*)(ab + (size_t)row * 256 + lane * 4);
            float mx = fmaxf(fmaxf(v4.x, v4.y), fmaxf(v4.z, v4.w));
            for (int d = 1; d < 64; d <<= 1) mx = fmaxf(mx, __shfl_xor(mx, d));
            float4 e4;
            e4.x = __expf(v4.x - mx); e4.y = __expf(v4.y - mx);
            e4.z = __expf(v4.z - mx); e4.w = __expf(v4.w - mx);
            float s = e4.x + e4.y + e4.z + e4.w;
            for (int d = 1; d < 64; d <<= 1) s += __shfl_xor(s, d);
            float rinv = 1.0f / s;
            e4.x *= rinv; e4.y *= rinv; e4.z *= rinv; e4.w *= rinv;
            *(float4*)(ab + (size_t)row * 256 + lane * 4) = e4;
            csum[0] += e4.x; csum[1] += e4.y; csum[2] += e4.z; csum[3] += e4.w;
        }
#pragma unroll
        for (int j = 0; j < 4; ++j)
            atomicAdd(&colsum[bh * 256 + lane * 4 + j], csum[j]);
    }
    gsync(bar, phase);

    // ---- Phase 2: denom = max(colsum) * max(rowsum=1) + 1e-8 ----
    if (gid == 0) {
        float m = 0.f;
        for (int i = t; i < 8192; i += 256) m = fmaxf(m, colsum[i]);
        float* red = (float*)smem;
        red[t] = m;
        __syncthreads();
        for (int s2 = 128; s2 > 0; s2 >>= 1) {
            if (t < s2) red[t] = fmaxf(red[t], red[t + s2]);
            __syncthreads();
        }
        if (t == 0) scal[2] = red[0] + 1e-8f;
    }
    gsync(bar, phase);

    // ---- Phase 3: zinit — z = attn2^T/denom (f32 via LDS transpose) + planes
    {
        float rdenom = 1.0f / scal[2];
        float* zb = zA + (size_t)bh * 65536;
        const float* a2b = attn2 + (size_t)bh * 65536;
        for (int p = 0; p < 2; ++p) {
            int rbase = n0 + 64 * p;
#pragma unroll
            for (int r = 0; r < 4; ++r) {
                int rowl = (t >> 4) + r * 16;
                int col4 = (t & 15) * 4;
                float4 a4 = *(const float4*)(a2b + (size_t)(rbase + rowl) * 256 +
                                             m0 + col4);
                a4.x *= rdenom; a4.y *= rdenom; a4.z *= rdenom; a4.w *= rdenom;
                Lf[(col4 + 0) * 68 + rowl] = a4.x;
                Lf[(col4 + 1) * 68 + rowl] = a4.y;
                Lf[(col4 + 2) * 68 + rowl] = a4.z;
                Lf[(col4 + 3) * 68 + rowl] = a4.w;
                uint2 ph, pl;
                split_pack4(a4.x, a4.y, a4.z, a4.w, ph, pl);
                size_t pidx = (size_t)bh * 65536 + (size_t)(rbase + rowl) * 256 +
                              m0 + col4;
                *(uint2*)&ZT0h[pidx] = ph;
                *(uint2*)&ZT0l[pidx] = pl;
            }
            __syncthreads();
            {
                int cl = t >> 2;
                int rc0 = (t & 3) * 16;
#pragma unroll
                for (int jj = 0; jj < 4; ++jj) {
                    int rc = rc0 + jj * 4;
                    float4 o = make_float4(Lf[cl * 68 + rc], Lf[cl * 68 + rc + 1],
                                           Lf[cl * 68 + rc + 2],
                                           Lf[cl * 68 + rc + 3]);
                    *(float4*)(zb + (size_t)(m0 + cl) * 256 + rbase + rc) = o;
                }
            }
            __syncthreads();
        }
    }
    gsync(bar, phase);

    // ---- Phase 4: 6 Newton-Schulz iterations (4 GEMM stages each) ----
    float* Zf[2] = {zA, zB};
    unsigned short* ZThA[2] = {ZT0h, ZT1h};
    unsigned short* ZTlA[2] = {ZT0l, ZT1l};
    int cur = 0;
    for (int it = 0; it < 6; ++it) {
        float* zc = Zf[cur];
        float* xz = Zf[1 - cur];
        pinv_stage(attn2, ZThA[cur], ZTlA[cur], xz, XZTh, XZTl, bh, m0, n0,
                   0, 0.f, 0.f, Ah, Al, Bh, Bl, t);
        gsync(bar, phase);
        pinv_stage(xz, XZTh, XZTl, nullptr, Y1Th, Y1Tl, bh, m0, n0,
                   1, -1.f, 7.f, Ah, Al, Bh, Bl, t);
        gsync(bar, phase);
        pinv_stage(xz, Y1Th, Y1Tl, nullptr, Y2Th, Y2Tl, bh, m0, n0,
                   1, -1.f, 15.f, Ah, Al, Bh, Bl, t);
        gsync(bar, phase);
        pinv_stage(zc, Y2Th, Y2Tl, xz, ZThA[1 - cur], ZTlA[1 - cur], bh, m0, n0,
                   1, -0.25f, 3.25f, Ah, Al, Bh, Bl, t);
        gsync(bar, phase);
        cur = 1 - cur;
    }

    // ---- Phase 5: t2 = zfin @ (t1/rs3) + t2^T planes (128 blocks) ----
    if (nt == 0) {
        const float* Azf = Zf[cur] + (size_t)bh * 65536;
        const float* Bb = t1 + (size_t)bh * 16384;
        const float* dv = rs3 + bh * 256;
        float* Cb = t2 + (size_t)bh * 16384;
        const int tx4 = (t & 15) * 4, ty4 = (t >> 4) * 4;
        const int ar = t >> 2, ak = (t & 3) * 4;
        const int bkr = t >> 4, bc4 = (t & 15) * 4;
        float acc[4][4] = {};
        for (int kt = 0; kt < 256; kt += 16) {
            float4 av = *(const float4*)(Azf + (size_t)(m0 + ar) * 256 + kt + ak);
            float4 bv = *(const float4*)(Bb + (size_t)(kt + bkr) * 64 + bc4);
            float rr = 1.0f / dv[kt + bkr];
            bv.x *= rr; bv.y *= rr; bv.z *= rr; bv.w *= rr;
            As[(ak + 0) * 68 + ar] = av.x;
            As[(ak + 1) * 68 + ar] = av.y;
            As[(ak + 2) * 68 + ar] = av.z;
            As[(ak + 3) * 68 + ar] = av.w;
            *(float4*)(Bs + bkr * 68 + bc4) = bv;
            __syncthreads();
            mt16(As, Bs, ty4, tx4, acc);
            __syncthreads();
        }
#pragma unroll
        for (int u = 0; u < 4; ++u)
            *(float4*)(Cb + (size_t)(m0 + ty4 + u) * 64 + tx4) =
                make_float4(acc[u][0], acc[u][1], acc[u][2], acc[u][3]);
#pragma unroll
        for (int w = 0; w < 4; ++w) {
            uint2 ph, pl;
            split_pack4(acc[0][w], acc[1][w], acc[2][w], acc[3][w], ph, pl);
            size_t off = (size_t)bh * 16384 + (size_t)(tx4 + w) * 256 + m0 + ty4;
            *(uint2*)&t2Th[off] = ph;
            *(uint2*)&t2Tl[off] = pl;
        }
    }
}

// ---------------------------------------------------------------------------
// prep: zero t1/rs3/scal/colsum + transpose/split both weights. grid 6208.
// ---------------------------------------------------------------------------
__global__ void prep(const float* __restrict__ wq, const float* __restrict__ wo,
                     float* __restrict__ zreg,
                     unsigned short* __restrict__ WQTh,
                     unsigned short* __restrict__ WQTl,
                     unsigned short* __restrict__ WOTh,
                     unsigned short* __restrict__ WOTl) {
    int b = blockIdx.x, t = threadIdx.x;
    if (b < 2112) {
        int i = b * 256 + t;
        if (i < 540688) zreg[i] = 0.f;
    } else if (b < 5184) {
        int i = (b - 2112) * 256 + t;
        int n = i >> 9, kk = i & 511;
        unsigned short h, l;
        split2(wq[(size_t)kk * 1536 + n], h, l);
        WQTh[i] = h;
        WQTl[i] = l;
    } else {
        int i = (b - 5184) * 256 + t;
        int n = i >> 9, kk = i & 511;
        unsigned short h, l;
        split2(wo[(size_t)kk * 512 + n], h, l);
        WOTh[i] = h;
        WOTl[i] = l;
    }
}

// merged landmark means for q and k. grid 4096.
__global__ void landmark2(const float* __restrict__ q,
                          const float* __restrict__ k,
                          float* __restrict__ ql, float* __restrict__ kl) {
    int o = blockIdx.x * 256 + threadIdx.x;
    const float* src;
    float* dst;
    int oo = o;
    if (o < 524288) { src = q; dst = ql; }
    else            { src = k; dst = kl; oo = o - 524288; }
    int d = oo & 63, m = (oo >> 6) & 255, bhx = oo >> 14;
    const float* s = src + (size_t)bhx * 262144 + (size_t)m * 1024 + d;
    float a = 0.f;
#pragma unroll
    for (int j = 0; j < 16; ++j) a += s[j * 64];
    dst[oo] = a * (1.0f / 16.0f);
}

// ---------------------------------------------------------------------------
// LDS-tiled depthwise conv: oh += conv33(v).  grid (32 tiles, 32 bh).
// ---------------------------------------------------------------------------
__global__ __launch_bounds__(256) void conv_tiled(
    float* __restrict__ oh, const float* __restrict__ v,
    const float* __restrict__ wres) {
    __shared__ float Vs[160 * 64];
    __shared__ float Ws[33];
    const int t = threadIdx.x;
    const int bh = blockIdx.y;
    const int n0 = blockIdx.x * 128;
    const int h = bh & 7;
    const float* vb = v + (size_t)bh * 262144;
    if (t < 33) Ws[t] = wres[h * 33 + t];
#pragma unroll
    for (int r = 0; r < 10; ++r) {
        int id = t + r * 256;
        int row = id >> 4, d4 = (id & 15) * 4;
        int n = n0 - 16 + row;
        float4 val = make_float4(0.f, 0.f, 0.f, 0.f);
        if ((unsigned)n < 4096u)
            val = *(const float4*)(vb + (size_t)n * 64 + d4);
        *(float4*)&Vs[row * 64 + d4] = val;
    }
    __syncthreads();
    const int d = t & 63;
    const int g0 = (t >> 6) * 32;
    float* ohb = oh + (size_t)bh * 262144 + (size_t)n0 * 64;
    float w[33];
#pragma unroll
    for (int j = 0; j < 33; ++j) w[j] = Vs[(g0 + j) * 64 + d];
#pragma unroll
    for (int i = 0; i < 32; ++i) {
        float acc = ohb[(size_t)(g0 + i) * 64 + d];
#pragma unroll
        for (int tt = 0; tt < 33; ++tt) acc += w[tt] * Ws[tt];
        ohb[(size_t)(g0 + i) * 64 + d] = acc;
        if (i < 31) {
#pragma unroll
            for (int j = 0; j < 32; ++j) w[j] = w[j + 1];
            w[32] = Vs[(g0 + i + 33) * 64 + d];
        }
    }
}

// ---------------------------------------------------------------------------
extern "C" void kernel_launch(void* const* d_in, const int* in_sizes, int n_in,
                              void* d_out, int out_size, void* d_ws, size_t ws_size,
                              hipStream_t stream) {
    const float* x     = (const float*)d_in[0];
    const float* w_qkv = (const float*)d_in[1];
    const float* w_out = (const float*)d_in[2];
    const float* w_res = (const float*)d_in[3];
    float* out = (float*)d_out;
    float* ws  = (float*)d_ws;

    float* q     = ws + O_Q;
    float* k     = ws + O_K;
    float* v     = ws + O_V;
    float* qland = ws + O_QL;
    float* kland = ws + O_KL;
    float* attn2 = ws + O_A2;
    float* t1    = ws + O_T1;
    float* rs3   = ws + O_RS3;
    float* scal  = ws + O_SCAL;
    float* t2    = ws + O_T2;
    float* zA    = k;
    float* zB    = k + SA;

    unsigned short* ZT0h = (unsigned short*)(ws + O_ZT0);
    unsigned short* ZT0l = (unsigned short*)(ws + O_ZT0 + SP);
    unsigned short* ZT1h = (unsigned short*)(ws + O_ZT1);
    unsigned short* ZT1l = (unsigned short*)(ws + O_ZT1 + SP);
    unsigned short* XZTh = (unsigned short*)(ws + O_XZT);
    unsigned short* XZTl = (unsigned short*)(ws + O_XZT + SP);
    unsigned short* Y1Th = (unsigned short*)(ws + O_Y1T);
    unsigned short* Y1Tl = (unsigned short*)(ws + O_Y1T + SP);
    unsigned short* Y2Th = (unsigned short*)(ws + O_Y2T);
    unsigned short* Y2Tl = (unsigned short*)(ws + O_Y2T + SP);
    unsigned short* WQTh = (unsigned short*)(ws + O_WQT);
    unsigned short* WQTl = (unsigned short*)(ws + O_WQT + 393216);
    unsigned short* WOTh = (unsigned short*)(ws + O_WOT);
    unsigned short* WOTl = (unsigned short*)(ws + O_WOT + 131072);
    unsigned short* vTh  = (unsigned short*)(ws + O_ZT1);   // 8 SP, pre-pinv
    unsigned short* vTl  = vTh + 8388608;
    unsigned short* t2Th = (unsigned short*)(ws + O_ZT1);   // post-pinv
    unsigned short* t2Tl = t2Th + 524288;
    unsigned* bar = (unsigned*)(scal + 8);

    // 1) zero t1/rs3/scal(+bar)/colsum + split-transpose both weights
    prep<<<6208, 256, 0, stream>>>(w_qkv, w_out, t1, WQTh, WQTl, WOTh, WOTl);

    // 2) qkv projection (+ head scatter, q scale, vT planes)
    mfma_qkv<<<dim3(12, 128), 256, 0, stream>>>(x, WQTh, WQTl, q, k, v,
                                                vTh, vTl);

    // 3) landmarks
    landmark2<<<4096, 256, 0, stream>>>(q, k, qland, kland);

    // 4) F3: t1_raw, rs3 (k and vT planes die here)
    attn3v_mfma<<<dim3(8, 4, 32), 256, 0, stream>>>(qland, k, vTh, vTl, t1, rs3);

    // 5) scores + softmax + pinv + t2, one resident kernel w/ sw grid barrier
    coop_pinv<<<256, 256, 0, stream>>>(
        attn2, qland, kland, zA, zB, ZT0h, ZT0l, ZT1h, ZT1l, XZTh, XZTl,
        Y1Th, Y1Tl, Y2Th, Y2Tl, t1, rs3, t2, t2Th, t2Tl, t2 /*colsum*/, scal,
        bar);

    // 6) F1: oh = softmax(q@kland^T)@t2 (in-place over q)
    attn1t2_mfma<<<dim3(64, 32), 256, 0, stream>>>(q, kland, t2Th, t2Tl, q);

    // 7) oh += depthwise conv(v)
    conv_tiled<<<dim3(32, 32), 256, 0, stream>>>(q, v, w_res);

    // 8) final projection
    mfma_final<<<dim3(4, 128), 256, 0, stream>>>(q, WOTh, WOTl, out);

    (void)in_sizes; (void)n_in; (void)out_size; (void)ws_size;
}

// Round 7
// 1030.456 us; speedup vs baseline: 2.2976x; 2.2976x over previous
//
#include <hip/hip_runtime.h>
#include <hip/hip_bf16.h>

// ---------------------------------------------------------------------------
// Nystrom attention: split-bf16 (hi/lo, 3xMFMA) for all large GEMMs.
// R7: revert R6's coop mega-kernel (grid-barrier design was 13x slower than
//     separate launches: 1.5% MfmaUtil, XCD-coherence thrash). Keep the safe
//     R6 deltas: HW-cvt split, merged prep/landmark kernels.
// B=4, N=4096, DIM=512, H=8, DH=64, M=256, l=16, 6 pinv iters, conv K=33.
// ---------------------------------------------------------------------------

typedef __attribute__((ext_vector_type(8))) short bf16x8;
typedef __attribute__((ext_vector_type(4))) float f32x4;

constexpr size_t SQ = 8388608;   // 32*4096*64
constexpr size_t SL = 524288;    // 32*256*64
constexpr size_t SA = 2097152;   // 32*256*256
constexpr size_t SP = 1048576;   // one bf16 plane of SA (float units)

constexpr size_t O_Q    = 0;                   // q -> later oh (in-place)
constexpr size_t O_K    = O_Q + SQ;            // k -> later zA,zB (f32)
constexpr size_t O_V    = O_K + SQ;
constexpr size_t O_QL   = O_V + SQ;
constexpr size_t O_KL   = O_QL + SL;
constexpr size_t O_A2   = O_KL + SL;
constexpr size_t O_T1   = O_A2 + SA;
constexpr size_t O_RS3  = O_T1 + SL;
constexpr size_t O_SCAL = O_RS3 + 8192;
constexpr size_t O_T2   = O_SCAL + 16;
constexpr size_t O_ZT0  = O_T2 + SL;
constexpr size_t O_ZT1  = O_ZT0 + 2 * SP;      // vT planes alias ZT1..Y2T (pre-pinv)
constexpr size_t O_XZT  = O_ZT1 + 2 * SP;      // t2T planes alias ZT1 (post-pinv)
constexpr size_t O_Y1T  = O_XZT + 2 * SP;
constexpr size_t O_Y2T  = O_Y1T + 2 * SP;
constexpr size_t O_WQT  = O_Y2T + 2 * SP;
constexpr size_t O_WOT  = O_WQT + 786432;
constexpr size_t O_END  = O_WOT + 262144;      // ~41M floats ~164 MB

// ---------------------------------------------------------------------------
__device__ __forceinline__ unsigned short bf16_rn(float x) {
    __hip_bfloat16 b = __float2bfloat16(x);    // HW RNE cvt
    unsigned short u;
    __builtin_memcpy(&u, &b, 2);
    return u;
}

__device__ __forceinline__ void split2(float x, unsigned short& h,
                                       unsigned short& l) {
    h = bf16_rn(x);
    float hf = __uint_as_float((unsigned)h << 16);
    l = bf16_rn(x - hf);
}

__device__ __forceinline__ void split_pack4(float a, float b, float c, float d,
                                            uint2& ph, uint2& pl) {
    unsigned short h0 = bf16_rn(a), h1 = bf16_rn(b);
    unsigned short h2 = bf16_rn(c), h3 = bf16_rn(d);
    ph.x = (unsigned)h0 | ((unsigned)h1 << 16);
    ph.y = (unsigned)h2 | ((unsigned)h3 << 16);
    float fa = __uint_as_float((unsigned)h0 << 16);
    float fb = __uint_as_float((unsigned)h1 << 16);
    float fc = __uint_as_float((unsigned)h2 << 16);
    float fd = __uint_as_float((unsigned)h3 << 16);
    unsigned short l0 = bf16_rn(a - fa), l1 = bf16_rn(b - fb);
    unsigned short l2 = bf16_rn(c - fc), l3 = bf16_rn(d - fd);
    pl.x = (unsigned)l0 | ((unsigned)l1 << 16);
    pl.y = (unsigned)l2 | ((unsigned)l3 << 16);
}

__device__ __forceinline__ void stage_split4(float4 av, unsigned short* H,
                                             unsigned short* L, int off) {
    uint2 ph, pl;
    split_pack4(av.x, av.y, av.z, av.w, ph, pl);
    *(uint2*)&H[off] = ph;
    *(uint2*)&L[off] = pl;
}

__device__ __forceinline__ f32x4 mfma3(bf16x8 ah, bf16x8 al, bf16x8 bh,
                                       bf16x8 bl, f32x4 c) {
    c = __builtin_amdgcn_mfma_f32_16x16x32_bf16(ah, bh, c, 0, 0, 0);
    c = __builtin_amdgcn_mfma_f32_16x16x32_bf16(ah, bl, c, 0, 0, 0);
    c = __builtin_amdgcn_mfma_f32_16x16x32_bf16(al, bh, c, 0, 0, 0);
    return c;
}

// ---------------------------------------------------------------------------
// pinv-family MFMA GEMM, 64x128 tile: C = alpha*(A@B) + beta*A_elem.
// A fp32 (split in-register); B = transposed bf16 planes BT[n][k].
// grid (2, 4, 32), block 256.
// ---------------------------------------------------------------------------
template <int EPI, bool WF32, bool WT>
__global__ __launch_bounds__(256) void mfma_gemm(
    const float* __restrict__ A, int lda, long saA,
    const unsigned short* __restrict__ BTh,
    const unsigned short* __restrict__ BTl, int ldbt, long sbT,
    float* __restrict__ C, int ldc, long scC,
    unsigned short* __restrict__ CTh, unsigned short* __restrict__ CTl,
    int ldct, long sct, int K, float alpha, float beta) {
    __shared__ unsigned short Ah[64 * 40], Al[64 * 40];
    __shared__ unsigned short Bh[128 * 40], Bl[128 * 40];
    const int t = threadIdx.x;
    const int wave = t >> 6, lane = t & 63, lm = lane & 15, lq = lane >> 4;
    const int z = blockIdx.z;
    const int m0 = blockIdx.y * 64, n0 = blockIdx.x * 128;
    const float* Ab = A + (size_t)z * saA;
    const unsigned short* BhB = BTh + (size_t)z * sbT;
    const unsigned short* BlB = BTl + (size_t)z * sbT;

    f32x4 acc[8];
#pragma unroll
    for (int j = 0; j < 8; ++j) acc[j] = (f32x4){0.f, 0.f, 0.f, 0.f};

    for (int kt = 0; kt < K; kt += 32) {
#pragma unroll
        for (int r = 0; r < 2; ++r) {
            int id = t + r * 256, row = id >> 3, k4 = (id & 7) * 4;
            float4 av = *(const float4*)(Ab + (size_t)(m0 + row) * lda + kt + k4);
            stage_split4(av, Ah, Al, row * 40 + k4);
        }
#pragma unroll
        for (int r = 0; r < 2; ++r) {
            int id = t + r * 256, row = id >> 2, ko = (id & 3) * 8;
            *(uint4*)&Bh[row * 40 + ko] =
                *(const uint4*)(BhB + (size_t)(n0 + row) * ldbt + kt + ko);
            *(uint4*)&Bl[row * 40 + ko] =
                *(const uint4*)(BlB + (size_t)(n0 + row) * ldbt + kt + ko);
        }
        __syncthreads();
        bf16x8 ah = *(const bf16x8*)&Ah[(wave * 16 + lm) * 40 + lq * 8];
        bf16x8 al = *(const bf16x8*)&Al[(wave * 16 + lm) * 40 + lq * 8];
#pragma unroll
        for (int j = 0; j < 8; ++j) {
            bf16x8 bh = *(const bf16x8*)&Bh[(j * 16 + lm) * 40 + lq * 8];
            bf16x8 bl = *(const bf16x8*)&Bl[(j * 16 + lm) * 40 + lq * 8];
            acc[j] = mfma3(ah, al, bh, bl, acc[j]);
        }
        __syncthreads();
    }

    float* Cb = C + (size_t)z * scC;
    unsigned short* CThB = CTh + (size_t)z * sct;
    unsigned short* CTlB = CTl + (size_t)z * sct;
    const int r0 = m0 + wave * 16 + lq * 4;
#pragma unroll
    for (int j = 0; j < 8; ++j) {
        int c = n0 + j * 16 + lm;
        float vals[4] = {acc[j][0], acc[j][1], acc[j][2], acc[j][3]};
        if (EPI == 1) {
#pragma unroll
            for (int e = 0; e < 4; ++e)
                vals[e] = alpha * vals[e] + beta * Ab[(size_t)(r0 + e) * lda + c];
        }
        if (WF32) {
#pragma unroll
            for (int e = 0; e < 4; ++e)
                Cb[(size_t)(r0 + e) * ldc + c] = vals[e];
        }
        if (WT) {
            uint2 ph, pl;
            split_pack4(vals[0], vals[1], vals[2], vals[3], ph, pl);
            *(uint2*)&CThB[(size_t)c * ldct + r0] = ph;
            *(uint2*)&CTlB[(size_t)c * ldct + r0] = pl;
        }
    }
}

// ---------------------------------------------------------------------------
// qkv MFMA GEMM: x[16384,512] @ w_qkv planes; scatters q(*0.125)/k/v AND
// emits vT split-bf16 planes [bh][dh][4096].  grid (12, 128).
// ---------------------------------------------------------------------------
__global__ __launch_bounds__(256) void mfma_qkv(
    const float* __restrict__ X, const unsigned short* __restrict__ WTh,
    const unsigned short* __restrict__ WTl, float* __restrict__ qb,
    float* __restrict__ kb, float* __restrict__ vb,
    unsigned short* __restrict__ vTh, unsigned short* __restrict__ vTl) {
    __shared__ unsigned short Ah[128 * 40], Al[128 * 40];
    __shared__ unsigned short Bh[128 * 40], Bl[128 * 40];
    const int t = threadIdx.x;
    const int wave = t >> 6, lane = t & 63, lm = lane & 15, lq = lane >> 4;
    const int m0 = blockIdx.y * 128, n0 = blockIdx.x * 128;
    const int mb = (wave >> 1) * 64, nb = (wave & 1) * 64;
    f32x4 acc[4][4];
#pragma unroll
    for (int i = 0; i < 4; ++i)
#pragma unroll
        for (int j = 0; j < 4; ++j) acc[i][j] = (f32x4){0.f, 0.f, 0.f, 0.f};

    for (int kt = 0; kt < 512; kt += 32) {
#pragma unroll
        for (int r = 0; r < 4; ++r) {
            int id = t + r * 256, row = id >> 3, k4 = (id & 7) * 4;
            float4 av = *(const float4*)(X + (size_t)(m0 + row) * 512 + kt + k4);
            stage_split4(av, Ah, Al, row * 40 + k4);
        }
#pragma unroll
        for (int r = 0; r < 2; ++r) {
            int id = t + r * 256, row = id >> 2, ko = (id & 3) * 8;
            *(uint4*)&Bh[row * 40 + ko] =
                *(const uint4*)(WTh + (size_t)(n0 + row) * 512 + kt + ko);
            *(uint4*)&Bl[row * 40 + ko] =
                *(const uint4*)(WTl + (size_t)(n0 + row) * 512 + kt + ko);
        }
        __syncthreads();
        bf16x8 ah[4], al[4], bh[4], bl[4];
#pragma unroll
        for (int i = 0; i < 4; ++i) {
            ah[i] = *(const bf16x8*)&Ah[(mb + i * 16 + lm) * 40 + lq * 8];
            al[i] = *(const bf16x8*)&Al[(mb + i * 16 + lm) * 40 + lq * 8];
        }
#pragma unroll
        for (int j = 0; j < 4; ++j) {
            bh[j] = *(const bf16x8*)&Bh[(nb + j * 16 + lm) * 40 + lq * 8];
            bl[j] = *(const bf16x8*)&Bl[(nb + j * 16 + lm) * 40 + lq * 8];
        }
#pragma unroll
        for (int i = 0; i < 4; ++i)
#pragma unroll
            for (int j = 0; j < 4; ++j)
                acc[i][j] = mfma3(ah[i], al[i], bh[j], bl[j], acc[i][j]);
        __syncthreads();
    }
#pragma unroll
    for (int i = 0; i < 4; ++i)
#pragma unroll
        for (int j = 0; j < 4; ++j) {
            int r0 = m0 + mb + i * 16 + lq * 4;
            int c  = n0 + nb + j * 16 + lm;
            int which = c >> 9, h = (c >> 6) & 7, d = c & 63;
            float sc = (which == 0) ? 0.125f : 1.0f;
            float* dst = (which == 0) ? qb : (which == 1 ? kb : vb);
            int b = r0 >> 12, nbase = r0 & 4095;
#pragma unroll
            for (int e = 0; e < 4; ++e)
                dst[(size_t)(b * 8 + h) * 262144 + (size_t)(nbase + e) * 64 + d] =
                    acc[i][j][e] * sc;
            if (which == 2) {
                uint2 ph, pl;
                split_pack4(acc[i][j][0], acc[i][j][1], acc[i][j][2],
                            acc[i][j][3], ph, pl);
                size_t off = ((size_t)(b * 8 + h) * 64 + d) * 4096 + nbase;
                *(uint2*)&vTh[off] = ph;
                *(uint2*)&vTl[off] = pl;
            }
        }
}

// ---------------------------------------------------------------------------
// final MFMA GEMM: out[16384,512] = oh(gathered) @ w_out planes. grid (4,128)
// ---------------------------------------------------------------------------
__global__ __launch_bounds__(256) void mfma_final(
    const float* __restrict__ OH, const unsigned short* __restrict__ WTh,
    const unsigned short* __restrict__ WTl, float* __restrict__ out) {
    __shared__ unsigned short Ah[128 * 40], Al[128 * 40];
    __shared__ unsigned short Bh[128 * 40], Bl[128 * 40];
    const int t = threadIdx.x;
    const int wave = t >> 6, lane = t & 63, lm = lane & 15, lq = lane >> 4;
    const int m0 = blockIdx.y * 128, n0 = blockIdx.x * 128;
    const int mb = (wave >> 1) * 64, nb = (wave & 1) * 64;
    f32x4 acc[4][4];
#pragma unroll
    for (int i = 0; i < 4; ++i)
#pragma unroll
        for (int j = 0; j < 4; ++j) acc[i][j] = (f32x4){0.f, 0.f, 0.f, 0.f};

    for (int kt = 0; kt < 512; kt += 32) {
#pragma unroll
        for (int r = 0; r < 4; ++r) {
            int id = t + r * 256, row = id >> 3, k4g = kt + (id & 7) * 4;
            int gr = m0 + row, b = gr >> 12, n = gr & 4095;
            float4 av = *(const float4*)(OH + (size_t)(b * 8 + (k4g >> 6)) * 262144 +
                                         (size_t)n * 64 + (k4g & 63));
            stage_split4(av, Ah, Al, row * 40 + (id & 7) * 4);
        }
#pragma unroll
        for (int r = 0; r < 2; ++r) {
            int id = t + r * 256, row = id >> 2, ko = (id & 3) * 8;
            *(uint4*)&Bh[row * 40 + ko] =
                *(const uint4*)(WTh + (size_t)(n0 + row) * 512 + kt + ko);
            *(uint4*)&Bl[row * 40 + ko] =
                *(const uint4*)(WTl + (size_t)(n0 + row) * 512 + kt + ko);
        }
        __syncthreads();
        bf16x8 ah[4], al[4], bh[4], bl[4];
#pragma unroll
        for (int i = 0; i < 4; ++i) {
            ah[i] = *(const bf16x8*)&Ah[(mb + i * 16 + lm) * 40 + lq * 8];
            al[i] = *(const bf16x8*)&Al[(mb + i * 16 + lm) * 40 + lq * 8];
        }
#pragma unroll
        for (int j = 0; j < 4; ++j) {
            bh[j] = *(const bf16x8*)&Bh[(nb + j * 16 + lm) * 40 + lq * 8];
            bl[j] = *(const bf16x8*)&Bl[(nb + j * 16 + lm) * 40 + lq * 8];
        }
#pragma unroll
        for (int i = 0; i < 4; ++i)
#pragma unroll
            for (int j = 0; j < 4; ++j)
                acc[i][j] = mfma3(ah[i], al[i], bh[j], bl[j], acc[i][j]);
        __syncthreads();
    }
#pragma unroll
    for (int i = 0; i < 4; ++i)
#pragma unroll
        for (int j = 0; j < 4; ++j) {
            int r0 = m0 + mb + i * 16 + lq * 4;
            int c  = n0 + nb + j * 16 + lm;
#pragma unroll
            for (int e = 0; e < 4; ++e)
                out[(size_t)(r0 + e) * 512 + c] = acc[i][j][e];
        }
}

// ---------------------------------------------------------------------------
// F3 MFMA: t1 += exp(qland@k^T)@v, rs3 += rowsums. grid (8, 4, 32).
// ---------------------------------------------------------------------------
__global__ __launch_bounds__(256) void attn3v_mfma(
    const float* __restrict__ qland, const float* __restrict__ k,
    const unsigned short* __restrict__ vTh,
    const unsigned short* __restrict__ vTl,
    float* __restrict__ t1, float* __restrict__ rs3) {
    __shared__ unsigned short Qh[4608], Ql[4608];
    __shared__ unsigned short Kh[4608], Kl[4608];
    __shared__ unsigned short Eh[4608], El[4608];
    const int t = threadIdx.x;
    const int wave = t >> 6, lane = t & 63, lm = lane & 15, lq = lane >> 4;
    const int bz = blockIdx.z, m0 = blockIdx.y * 64, c0 = blockIdx.x * 8;
    const float* qb = qland + (size_t)bz * 16384;
    const float* kb = k + (size_t)bz * 262144;
    const unsigned short* vhb = vTh + (size_t)bz * 262144;
    const unsigned short* vlb = vTl + (size_t)bz * 262144;
#pragma unroll
    for (int r = 0; r < 4; ++r) {
        int id = t + r * 256, row = id >> 4, d4 = (id & 15) * 4;
        float4 av = *(const float4*)(qb + (size_t)(m0 + row) * 64 + d4);
        stage_split4(av, Qh, Ql, row * 72 + d4);
    }
    f32x4 acc[4];
#pragma unroll
    for (int j = 0; j < 4; ++j) acc[j] = (f32x4){0.f, 0.f, 0.f, 0.f};
    float rsum[4] = {0.f, 0.f, 0.f, 0.f};
    __syncthreads();

    for (int c = c0; c < c0 + 8; ++c) {
        const int tok0 = c * 64;
#pragma unroll
        for (int r = 0; r < 4; ++r) {
            int id = t + r * 256, row = id >> 4, d4 = (id & 15) * 4;
            float4 kv = *(const float4*)(kb + (size_t)(tok0 + row) * 64 + d4);
            stage_split4(kv, Kh, Kl, row * 72 + d4);
        }
        __syncthreads();
        bf16x8 a0  = *(const bf16x8*)&Qh[(wave * 16 + lm) * 72 + lq * 8];
        bf16x8 a0l = *(const bf16x8*)&Ql[(wave * 16 + lm) * 72 + lq * 8];
        bf16x8 a1  = *(const bf16x8*)&Qh[(wave * 16 + lm) * 72 + 32 + lq * 8];
        bf16x8 a1l = *(const bf16x8*)&Ql[(wave * 16 + lm) * 72 + 32 + lq * 8];
        f32x4 s[4];
#pragma unroll
        for (int j = 0; j < 4; ++j) s[j] = (f32x4){0.f, 0.f, 0.f, 0.f};
#pragma unroll
        for (int j = 0; j < 4; ++j) {
            bf16x8 b0  = *(const bf16x8*)&Kh[(j * 16 + lm) * 72 + lq * 8];
            bf16x8 b0l = *(const bf16x8*)&Kl[(j * 16 + lm) * 72 + lq * 8];
            bf16x8 b1  = *(const bf16x8*)&Kh[(j * 16 + lm) * 72 + 32 + lq * 8];
            bf16x8 b1l = *(const bf16x8*)&Kl[(j * 16 + lm) * 72 + 32 + lq * 8];
            s[j] = mfma3(a0, a0l, b0, b0l, s[j]);
            s[j] = mfma3(a1, a1l, b1, b1l, s[j]);
        }
        __syncthreads();
#pragma unroll
        for (int j = 0; j < 4; ++j)
#pragma unroll
            for (int e = 0; e < 4; ++e) {
                float ev = __expf(s[j][e]);
                rsum[e] += ev;
                unsigned short h, l;
                split2(ev, h, l);
                int off = (wave * 16 + lq * 4 + e) * 72 + j * 16 + lm;
                Eh[off] = h;
                El[off] = l;
            }
#pragma unroll
        for (int r = 0; r < 2; ++r) {
            int id = t + r * 256, dh = id >> 3, t8 = (id & 7) * 8;
            *(uint4*)&Kh[dh * 72 + t8] =
                *(const uint4*)(vhb + (size_t)dh * 4096 + tok0 + t8);
            *(uint4*)&Kl[dh * 72 + t8] =
                *(const uint4*)(vlb + (size_t)dh * 4096 + tok0 + t8);
        }
        __syncthreads();
        bf16x8 e0  = *(const bf16x8*)&Eh[(wave * 16 + lm) * 72 + lq * 8];
        bf16x8 e0l = *(const bf16x8*)&El[(wave * 16 + lm) * 72 + lq * 8];
        bf16x8 e1  = *(const bf16x8*)&Eh[(wave * 16 + lm) * 72 + 32 + lq * 8];
        bf16x8 e1l = *(const bf16x8*)&El[(wave * 16 + lm) * 72 + 32 + lq * 8];
#pragma unroll
        for (int j = 0; j < 4; ++j) {
            bf16x8 v0  = *(const bf16x8*)&Kh[(j * 16 + lm) * 72 + lq * 8];
            bf16x8 v0l = *(const bf16x8*)&Kl[(j * 16 + lm) * 72 + lq * 8];
            bf16x8 v1  = *(const bf16x8*)&Kh[(j * 16 + lm) * 72 + 32 + lq * 8];
            bf16x8 v1l = *(const bf16x8*)&Kl[(j * 16 + lm) * 72 + 32 + lq * 8];
            acc[j] = mfma3(e0, e0l, v0, v0l, acc[j]);
            acc[j] = mfma3(e1, e1l, v1, v1l, acc[j]);
        }
        __syncthreads();
    }
    float* t1b = t1 + (size_t)bz * 16384;
#pragma unroll
    for (int j = 0; j < 4; ++j)
#pragma unroll
        for (int e = 0; e < 4; ++e)
            atomicAdd(t1b + (size_t)(m0 + wave * 16 + lq * 4 + e) * 64 +
                          j * 16 + lm,
                      acc[j][e]);
#pragma unroll
    for (int e = 0; e < 4; ++e) {
        float vs = rsum[e];
        for (int mm = 1; mm < 16; mm <<= 1) vs += __shfl_xor(vs, mm);
        if (lm == 0)
            atomicAdd(rs3 + bz * 256 + m0 + wave * 16 + lq * 4 + e, vs);
    }
}

// ---------------------------------------------------------------------------
// F1 MFMA: oh = softmax(q@kland^T) @ t2 (normalized), in-place over q.
// grid (64, 32).
// ---------------------------------------------------------------------------
__global__ __launch_bounds__(256) void attn1t2_mfma(
    const float* __restrict__ q, const float* __restrict__ kland,
    const unsigned short* __restrict__ t2Th,
    const unsigned short* __restrict__ t2Tl, float* __restrict__ oh) {
    __shared__ unsigned short Qh[4608], Ql[4608];
    __shared__ unsigned short Kh[4608], Kl[4608];
    __shared__ unsigned short Eh[4608], El[4608];
    const int t = threadIdx.x;
    const int wave = t >> 6, lane = t & 63, lm = lane & 15, lq = lane >> 4;
    const int bz = blockIdx.y, m0 = blockIdx.x * 64;
    const float* qb  = q + (size_t)bz * 262144;
    const float* klb = kland + (size_t)bz * 16384;
    const unsigned short* t2h = t2Th + (size_t)bz * 16384;
    const unsigned short* t2l = t2Tl + (size_t)bz * 16384;
#pragma unroll
    for (int r = 0; r < 4; ++r) {
        int id = t + r * 256, row = id >> 4, d4 = (id & 15) * 4;
        float4 av = *(const float4*)(qb + (size_t)(m0 + row) * 64 + d4);
        stage_split4(av, Qh, Ql, row * 72 + d4);
    }
    f32x4 acc[4];
#pragma unroll
    for (int j = 0; j < 4; ++j) acc[j] = (f32x4){0.f, 0.f, 0.f, 0.f};
    float rsum[4] = {0.f, 0.f, 0.f, 0.f};
    __syncthreads();

    for (int lc = 0; lc < 4; ++lc) {
        const int l0 = lc * 64;
#pragma unroll
        for (int r = 0; r < 4; ++r) {
            int id = t + r * 256, row = id >> 4, d4 = (id & 15) * 4;
            float4 kv = *(const float4*)(klb + (size_t)(l0 + row) * 64 + d4);
            stage_split4(kv, Kh, Kl, row * 72 + d4);
        }
        __syncthreads();
        bf16x8 a0  = *(const bf16x8*)&Qh[(wave * 16 + lm) * 72 + lq * 8];
        bf16x8 a0l = *(const bf16x8*)&Ql[(wave * 16 + lm) * 72 + lq * 8];
        bf16x8 a1  = *(const bf16x8*)&Qh[(wave * 16 + lm) * 72 + 32 + lq * 8];
        bf16x8 a1l = *(const bf16x8*)&Ql[(wave * 16 + lm) * 72 + 32 + lq * 8];
        f32x4 s[4];
#pragma unroll
        for (int j = 0; j < 4; ++j) s[j] = (f32x4){0.f, 0.f, 0.f, 0.f};
#pragma unroll
        for (int j = 0; j < 4; ++j) {
            bf16x8 b0  = *(const bf16x8*)&Kh[(j * 16 + lm) * 72 + lq * 8];
            bf16x8 b0l = *(const bf16x8*)&Kl[(j * 16 + lm) * 72 + lq * 8];
            bf16x8 b1  = *(const bf16x8*)&Kh[(j * 16 + lm) * 72 + 32 + lq * 8];
            bf16x8 b1l = *(const bf16x8*)&Kl[(j * 16 + lm) * 72 + 32 + lq * 8];
            s[j] = mfma3(a0, a0l, b0, b0l, s[j]);
            s[j] = mfma3(a1, a1l, b1, b1l, s[j]);
        }
        __syncthreads();
#pragma unroll
        for (int j = 0; j < 4; ++j)
#pragma unroll
            for (int e = 0; e < 4; ++e) {
                float ev = __expf(s[j][e]);
                rsum[e] += ev;
                unsigned short h, l;
                split2(ev, h, l);
                int off = (wave * 16 + lq * 4 + e) * 72 + j * 16 + lm;
                Eh[off] = h;
                El[off] = l;
            }
#pragma unroll
        for (int r = 0; r < 2; ++r) {
            int id = t + r * 256, dh = id >> 3, t8 = (id & 7) * 8;
            *(uint4*)&Kh[dh * 72 + t8] =
                *(const uint4*)(t2h + (size_t)dh * 256 + l0 + t8);
            *(uint4*)&Kl[dh * 72 + t8] =
                *(const uint4*)(t2l + (size_t)dh * 256 + l0 + t8);
        }
        __syncthreads();
        bf16x8 e0  = *(const bf16x8*)&Eh[(wave * 16 + lm) * 72 + lq * 8];
        bf16x8 e0l = *(const bf16x8*)&El[(wave * 16 + lm) * 72 + lq * 8];
        bf16x8 e1  = *(const bf16x8*)&Eh[(wave * 16 + lm) * 72 + 32 + lq * 8];
        bf16x8 e1l = *(const bf16x8*)&El[(wave * 16 + lm) * 72 + 32 + lq * 8];
#pragma unroll
        for (int j = 0; j < 4; ++j) {
            bf16x8 v0  = *(const bf16x8*)&Kh[(j * 16 + lm) * 72 + lq * 8];
            bf16x8 v0l = *(const bf16x8*)&Kl[(j * 16 + lm) * 72 + lq * 8];
            bf16x8 v1  = *(const bf16x8*)&Kh[(j * 16 + lm) * 72 + 32 + lq * 8];
            bf16x8 v1l = *(const bf16x8*)&Kl[(j * 16 + lm) * 72 + 32 + lq * 8];
            acc[j] = mfma3(e0, e0l, v0, v0l, acc[j]);
            acc[j] = mfma3(e1, e1l, v1, v1l, acc[j]);
        }
        __syncthreads();
    }
    float rinv[4];
#pragma unroll
    for (int e = 0; e < 4; ++e) {
        float vs = rsum[e];
        for (int mm = 1; mm < 16; mm <<= 1) vs += __shfl_xor(vs, mm);
        rinv[e] = 1.0f / vs;
    }
    float* ohb = oh + (size_t)bz * 262144;
#pragma unroll
    for (int j = 0; j < 4; ++j)
#pragma unroll
        for (int e = 0; e < 4; ++e)
            ohb[(size_t)(m0 + wave * 16 + lq * 4 + e) * 64 + j * 16 + lm] =
                acc[j][e] * rinv[e];
}

// ---------------------------------------------------------------------------
// fp32 64x64 micro-kernel + gemm_bk (attn2 scores + t2 only)
// ---------------------------------------------------------------------------
__device__ __forceinline__ void mt16(const float* As, const float* Bs,
                                     int ty4, int tx4, float (&acc)[4][4]) {
#pragma unroll
    for (int kk = 0; kk < 16; ++kk) {
        float4 a4 = *(const float4*)(As + kk * 68 + ty4);
        float4 b4 = *(const float4*)(Bs + kk * 68 + tx4);
        float aa[4] = {a4.x, a4.y, a4.z, a4.w};
        float bb[4] = {b4.x, b4.y, b4.z, b4.w};
#pragma unroll
        for (int u = 0; u < 4; ++u)
#pragma unroll
            for (int w = 0; w < 4; ++w)
                acc[u][w] += aa[u] * bb[w];
    }
}

template <bool TRANSB, bool DIVB, bool WTOUT>
__global__ __launch_bounds__(256) void gemm_bk(
    const float* __restrict__ A, int saA, int lda,
    const float* __restrict__ B, int sbB, int ldb,
    float* __restrict__ C, int scC, int ldc,
    int K, const float* __restrict__ divv,
    unsigned short* __restrict__ CTh, unsigned short* __restrict__ CTl) {
    __shared__ float As[16 * 68];
    __shared__ float Bs[16 * 68];
    const int t  = threadIdx.x;
    const int z  = blockIdx.z;
    const int m0 = blockIdx.y * 64;
    const int n0 = blockIdx.x * 64;
    const float* Ab = A + (size_t)z * saA;
    const float* Bb = B + (size_t)z * sbB;
    float*       Cb = C + (size_t)z * scC;
    const int tx4 = (t & 15) * 4;
    const int ty4 = (t >> 4) * 4;
    const int ar  = t >> 2, ak = (t & 3) * 4;
    const int bkr = t >> 4, bc4 = (t & 15) * 4;
    float acc[4][4] = {};
    for (int kt = 0; kt < K; kt += 16) {
        float4 av = *(const float4*)(Ab + (size_t)(m0 + ar) * lda + kt + ak);
        float4 bv;
        if (TRANSB) {
            bv = *(const float4*)(Bb + (size_t)(n0 + ar) * ldb + kt + ak);
        } else {
            bv = *(const float4*)(Bb + (size_t)(kt + bkr) * ldb + n0 + bc4);
            if (DIVB) {
                float r = 1.0f / divv[z * K + kt + bkr];
                bv.x *= r; bv.y *= r; bv.z *= r; bv.w *= r;
            }
        }
        As[(ak + 0) * 68 + ar] = av.x;
        As[(ak + 1) * 68 + ar] = av.y;
        As[(ak + 2) * 68 + ar] = av.z;
        As[(ak + 3) * 68 + ar] = av.w;
        if (TRANSB) {
            Bs[(ak + 0) * 68 + ar] = bv.x;
            Bs[(ak + 1) * 68 + ar] = bv.y;
            Bs[(ak + 2) * 68 + ar] = bv.z;
            Bs[(ak + 3) * 68 + ar] = bv.w;
        } else {
            *(float4*)(Bs + bkr * 68 + bc4) = bv;
        }
        __syncthreads();
        mt16(As, Bs, ty4, tx4, acc);
        __syncthreads();
    }
#pragma unroll
    for (int u = 0; u < 4; ++u) {
        int row = m0 + ty4 + u;
        *(float4*)(Cb + (size_t)row * ldc + n0 + tx4) =
            make_float4(acc[u][0], acc[u][1], acc[u][2], acc[u][3]);
    }
    if (WTOUT) {
#pragma unroll
        for (int w = 0; w < 4; ++w) {
            uint2 ph, pl;
            split_pack4(acc[0][w], acc[1][w], acc[2][w], acc[3][w], ph, pl);
            size_t off = (size_t)z * 16384 + (size_t)(n0 + tx4 + w) * 256 +
                         m0 + ty4;
            *(uint2*)&CTh[off] = ph;
            *(uint2*)&CTl[off] = pl;
        }
    }
}

// ---------------------------------------------------------------------------
// small kernels
// ---------------------------------------------------------------------------
// prep: zero t1/rs3/scal + transpose/split both weights. grid 6177.
__global__ void prep(const float* __restrict__ wq, const float* __restrict__ wo,
                     float* __restrict__ zreg,
                     unsigned short* __restrict__ WQTh,
                     unsigned short* __restrict__ WQTl,
                     unsigned short* __restrict__ WOTh,
                     unsigned short* __restrict__ WOTl) {
    int b = blockIdx.x, t = threadIdx.x;
    if (b < 2081) {
        int i = b * 256 + t;
        if (i < 532496) zreg[i] = 0.f;
    } else if (b < 5153) {
        int i = (b - 2081) * 256 + t;
        int n = i >> 9, kk = i & 511;
        unsigned short h, l;
        split2(wq[(size_t)kk * 1536 + n], h, l);
        WQTh[i] = h;
        WQTl[i] = l;
    } else {
        int i = (b - 5153) * 256 + t;
        int n = i >> 9, kk = i & 511;
        unsigned short h, l;
        split2(wo[(size_t)kk * 512 + n], h, l);
        WOTh[i] = h;
        WOTl[i] = l;
    }
}

// merged landmark means for q and k. grid 4096.
__global__ void landmark2(const float* __restrict__ q,
                          const float* __restrict__ k,
                          float* __restrict__ ql, float* __restrict__ kl) {
    int o = blockIdx.x * 256 + threadIdx.x;
    const float* src;
    float* dst;
    int oo = o;
    if (o < 524288) { src = q; dst = ql; }
    else            { src = k; dst = kl; oo = o - 524288; }
    int d = oo & 63, m = (oo >> 6) & 255, bhx = oo >> 14;
    const float* s = src + (size_t)bhx * 262144 + (size_t)m * 1024 + d;
    float a = 0.f;
#pragma unroll
    for (int j = 0; j < 16; ++j) a += s[j * 64];
    dst[oo] = a * (1.0f / 16.0f);
}

__global__ void softmax_rows(float* __restrict__ a) {
    __shared__ float red[256];
    int row = blockIdx.x, t = threadIdx.x;
    float v = a[(size_t)row * 256 + t];
    red[t] = v;
    __syncthreads();
    for (int s = 128; s > 0; s >>= 1) {
        if (t < s) red[t] = fmaxf(red[t], red[t + s]);
        __syncthreads();
    }
    float mx = red[0];
    __syncthreads();
    float e = __expf(v - mx);
    red[t] = e;
    __syncthreads();
    for (int s = 128; s > 0; s >>= 1) {
        if (t < s) red[t] += red[t + s];
        __syncthreads();
    }
    a[(size_t)row * 256 + t] = e / red[0];
}

__global__ __launch_bounds__(256) void scalar_prep(const float* __restrict__ a,
                                                   float* __restrict__ scal) {
    __shared__ float red[256];
    int bh = blockIdx.x, t = threadIdx.x;
    const float* ab = a + (size_t)bh * 65536;
    float cs = 0.f;
    for (int i = 0; i < 256; ++i) cs += ab[i * 256 + t];
    red[t] = cs;
    __syncthreads();
    for (int s = 128; s > 0; s >>= 1) {
        if (t < s) red[t] = fmaxf(red[t], red[t + s]);
        __syncthreads();
    }
    float mcol = red[0];
    __syncthreads();
    float rs = 0.f;
    for (int j = 0; j < 256; ++j) rs += ab[t * 256 + j];
    red[t] = rs;
    __syncthreads();
    for (int s = 128; s > 0; s >>= 1) {
        if (t < s) red[t] = fmaxf(red[t], red[t + s]);
        __syncthreads();
    }
    if (t == 0) {
        atomicMax((unsigned int*)&scal[0], __float_as_uint(mcol));
        atomicMax((unsigned int*)&scal[1], __float_as_uint(red[0]));
    }
}

__global__ void zinit(const float* __restrict__ a, float* __restrict__ zz,
                      unsigned short* __restrict__ zTh,
                      unsigned short* __restrict__ zTl,
                      const float* __restrict__ scal) {
    int idx = blockIdx.x * 256 + threadIdx.x;
    int bh = idx >> 16, r = (idx >> 8) & 255, c = idx & 255;
    float denom = scal[0] * scal[1] + 1e-8f;
    float v = a[idx] / denom;
    zz[((size_t)bh << 16) + ((size_t)c << 8) + r] = v;
    unsigned short h, l;
    split2(v, h, l);
    zTh[idx] = h;
    zTl[idx] = l;
}

// ---------------------------------------------------------------------------
// LDS-tiled depthwise conv: oh += conv33(v).  grid (32 tiles, 32 bh).
// ---------------------------------------------------------------------------
__global__ __launch_bounds__(256) void conv_tiled(
    float* __restrict__ oh, const float* __restrict__ v,
    const float* __restrict__ wres) {
    __shared__ float Vs[160 * 64];
    __shared__ float Ws[33];
    const int t = threadIdx.x;
    const int bh = blockIdx.y;
    const int n0 = blockIdx.x * 128;
    const int h = bh & 7;
    const float* vb = v + (size_t)bh * 262144;
    if (t < 33) Ws[t] = wres[h * 33 + t];
#pragma unroll
    for (int r = 0; r < 10; ++r) {
        int id = t + r * 256;
        int row = id >> 4, d4 = (id & 15) * 4;
        int n = n0 - 16 + row;
        float4 val = make_float4(0.f, 0.f, 0.f, 0.f);
        if ((unsigned)n < 4096u)
            val = *(const float4*)(vb + (size_t)n * 64 + d4);
        *(float4*)&Vs[row * 64 + d4] = val;
    }
    __syncthreads();
    const int d = t & 63;
    const int g0 = (t >> 6) * 32;
    float* ohb = oh + (size_t)bh * 262144 + (size_t)n0 * 64;
    float w[33];
#pragma unroll
    for (int j = 0; j < 33; ++j) w[j] = Vs[(g0 + j) * 64 + d];
#pragma unroll
    for (int i = 0; i < 32; ++i) {
        float acc = ohb[(size_t)(g0 + i) * 64 + d];
#pragma unroll
        for (int tt = 0; tt < 33; ++tt) acc += w[tt] * Ws[tt];
        ohb[(size_t)(g0 + i) * 64 + d] = acc;
        if (i < 31) {
#pragma unroll
            for (int j = 0; j < 32; ++j) w[j] = w[j + 1];
            w[32] = Vs[(g0 + i + 33) * 64 + d];
        }
    }
}

// ---------------------------------------------------------------------------
extern "C" void kernel_launch(void* const* d_in, const int* in_sizes, int n_in,
                              void* d_out, int out_size, void* d_ws, size_t ws_size,
                              hipStream_t stream) {
    const float* x     = (const float*)d_in[0];
    const float* w_qkv = (const float*)d_in[1];
    const float* w_out = (const float*)d_in[2];
    const float* w_res = (const float*)d_in[3];
    float* out = (float*)d_out;
    float* ws  = (float*)d_ws;

    float* q     = ws + O_Q;
    float* k     = ws + O_K;
    float* v     = ws + O_V;
    float* qland = ws + O_QL;
    float* kland = ws + O_KL;
    float* attn2 = ws + O_A2;
    float* t1    = ws + O_T1;
    float* rs3   = ws + O_RS3;
    float* scal  = ws + O_SCAL;
    float* t2    = ws + O_T2;
    float* zA    = k;
    float* zB    = k + SA;

    unsigned short* ZT0h = (unsigned short*)(ws + O_ZT0);
    unsigned short* ZT0l = (unsigned short*)(ws + O_ZT0 + SP);
    unsigned short* ZT1h = (unsigned short*)(ws + O_ZT1);
    unsigned short* ZT1l = (unsigned short*)(ws + O_ZT1 + SP);
    unsigned short* XZTh = (unsigned short*)(ws + O_XZT);
    unsigned short* XZTl = (unsigned short*)(ws + O_XZT + SP);
    unsigned short* Y1Th = (unsigned short*)(ws + O_Y1T);
    unsigned short* Y1Tl = (unsigned short*)(ws + O_Y1T + SP);
    unsigned short* Y2Th = (unsigned short*)(ws + O_Y2T);
    unsigned short* Y2Tl = (unsigned short*)(ws + O_Y2T + SP);
    unsigned short* WQTh = (unsigned short*)(ws + O_WQT);
    unsigned short* WQTl = (unsigned short*)(ws + O_WQT + 393216);
    unsigned short* WOTh = (unsigned short*)(ws + O_WOT);
    unsigned short* WOTl = (unsigned short*)(ws + O_WOT + 131072);
    unsigned short* vTh  = (unsigned short*)(ws + O_ZT1);   // 8 SP, pre-pinv
    unsigned short* vTl  = vTh + 8388608;
    unsigned short* t2Th = (unsigned short*)(ws + O_ZT1);   // post-pinv
    unsigned short* t2Tl = t2Th + 524288;

    // 1) zero t1/rs3/scal + split-transpose both weights
    prep<<<6177, 256, 0, stream>>>(w_qkv, w_out, t1, WQTh, WQTl, WOTh, WOTl);

    // 2) qkv projection (+ head scatter, q scale, vT planes)
    mfma_qkv<<<dim3(12, 128), 256, 0, stream>>>(x, WQTh, WQTl, q, k, v,
                                                vTh, vTl);

    // 3) landmarks
    landmark2<<<4096, 256, 0, stream>>>(q, k, qland, kland);

    // 4) attn2 scores + softmax + pinv scalars
    gemm_bk<true, false, false><<<dim3(4, 4, 32), 256, 0, stream>>>(
        qland, 16384, 64, kland, 16384, 64, attn2, 65536, 256, 64, nullptr,
        nullptr, nullptr);
    softmax_rows<<<8192, 256, 0, stream>>>(attn2);
    scalar_prep<<<32, 256, 0, stream>>>(attn2, scal);

    // 5) F3: t1_raw, rs3 (k and vT planes die here)
    attn3v_mfma<<<dim3(8, 4, 32), 256, 0, stream>>>(qland, k, vTh, vTl, t1, rs3);

    // 6) pinv init + 6 Newton-Schulz iterations (separate launches — measured
    //    faster than resident grid-sync design on this chip, see R6)
    zinit<<<8192, 256, 0, stream>>>(attn2, zA, ZT0h, ZT0l, scal);

    unsigned short* ZTh[2] = {ZT0h, ZT1h};
    unsigned short* ZTl[2] = {ZT0l, ZT1l};
    float* Zf[2] = {zA, zB};
    int cur = 0;
    const dim3 pg(2, 4, 32);
    for (int it = 0; it < 6; ++it) {
        float* zc  = Zf[cur];
        float* xzf = Zf[1 - cur];
        mfma_gemm<0, true, true><<<pg, 256, 0, stream>>>(
            attn2, 256, 65536, ZTh[cur], ZTl[cur], 256, 65536,
            xzf, 256, 65536, XZTh, XZTl, 256, 65536, 256, 0.f, 0.f);
        mfma_gemm<1, false, true><<<pg, 256, 0, stream>>>(
            xzf, 256, 65536, XZTh, XZTl, 256, 65536,
            nullptr, 256, 65536, Y1Th, Y1Tl, 256, 65536, 256, -1.f, 7.f);
        mfma_gemm<1, false, true><<<pg, 256, 0, stream>>>(
            xzf, 256, 65536, Y1Th, Y1Tl, 256, 65536,
            nullptr, 256, 65536, Y2Th, Y2Tl, 256, 65536, 256, -1.f, 15.f);
        mfma_gemm<1, true, true><<<pg, 256, 0, stream>>>(
            zc, 256, 65536, Y2Th, Y2Tl, 256, 65536,
            xzf, 256, 65536, ZTh[1 - cur], ZTl[1 - cur], 256, 65536,
            256, -0.25f, 3.25f);
        cur = 1 - cur;
    }
    float* zfin = Zf[cur];

    // 7) t2 = z @ (t1 / rs3); also emit t2^T split planes
    gemm_bk<false, true, true><<<dim3(1, 4, 32), 256, 0, stream>>>(
        zfin, 65536, 256, t1, 16384, 64, t2, 16384, 64, 256, rs3,
        t2Th, t2Tl);

    // 8) F1: oh = softmax(q@kland^T)@t2 (in-place over q)
    attn1t2_mfma<<<dim3(64, 32), 256, 0, stream>>>(q, kland, t2Th, t2Tl, q);

    // 9) oh += depthwise conv(v)
    conv_tiled<<<dim3(32, 32), 256, 0, stream>>>(q, v, w_res);

    // 10) final projection
    mfma_final<<<dim3(4, 128), 256, 0, stream>>>(q, WOTh, WOTl, out);

    (void)in_sizes; (void)n_in; (void)out_size; (void)ws_size;
}